// Round 4
// baseline (3452.185 us; speedup 1.0000x reference)
//
#include <hip/hip_runtime.h>

#define N_NODES 100000
#define N_EDGES 1600000
#define DIM 128

#define BK_BITS 7                 // 128 nodes per bucket
#define BK_NODES 128
#define NBK ((N_NODES + BK_NODES - 1) / BK_NODES)   // 782
#define BCAP 4096                 // bucket capacity (mean 2046, sd ~45)

// ===========================================================================
// Bucket scatter: one packed word per edge into its dst-bucket's region.
// word = (dst_low7 << 17) | src   (src < 2^17). Fixed-capacity regions, so
// no degree pass / scan needed. Bucket-local appends give L2 write merging.
// ===========================================================================
__global__ __launch_bounds__(256) void bfill_k(const int* __restrict__ ei,
                                               int* __restrict__ bcursor,
                                               int* __restrict__ bbuf)
{
    int e = blockIdx.x * 256 + threadIdx.x;
    if (e >= N_EDGES) return;
    int src = ei[e];
    int dst = ei[N_EDGES + e];
    int b = dst >> BK_BITS;
    int pos = atomicAdd(bcursor + b, 1);
    if (pos < BCAP) bbuf[b * BCAP + pos] = ((dst & (BK_NODES - 1)) << 17) | src;
}

// ===========================================================================
// Fused aggregation: one block per bucket. 128x128 fp32 accumulator in LDS
// (64 KB). Each wave pulls 64 packed edges coalesced (one per lane),
// broadcasts each via readlane, gathers x[src] (lane l covers ch l, l+64 ->
// LDS bank = lane%32, 2-way = free), LDS-atomic accumulates. Degree from an
// LDS histogram (1 atomic per lane per 64-edge batch). Finalize writes
// a[n] = x[n] + acc[n]/max(deg,1).
// ===========================================================================
__global__ __launch_bounds__(512) void agg_fused_k(const float* __restrict__ x,
                                                   const int* __restrict__ bcursor,
                                                   const int* __restrict__ bbuf,
                                                   float* __restrict__ a)
{
    __shared__ float acc[BK_NODES * DIM];    // 64 KB
    __shared__ int cnt[BK_NODES];

    const int t = threadIdx.x;
    const int w = t >> 6;                     // wave 0..7
    const int lane = t & 63;

    for (int i = t; i < BK_NODES * DIM / 4; i += 512)
        ((float4*)acc)[i] = make_float4(0.f, 0.f, 0.f, 0.f);
    if (t < BK_NODES) cnt[t] = 0;
    __syncthreads();

    const int b = blockIdx.x;
    int n = bcursor[b];
    if (n > BCAP) n = BCAP;
    const int* bp = bbuf + b * BCAP;

    // full 64-edge batches, waves round-robin over 64-edge chunks
    int base;
    for (base = w * 64; base + 64 <= n; base += 512) {
        int myw = bp[base + lane];                       // coalesced
        atomicAdd(&cnt[myw >> 17], 1);                   // degree histogram
        #pragma unroll 1
        for (int j = 0; j < 64; j += 8) {
            #pragma unroll
            for (int u = 0; u < 8; ++u) {
                int word = __builtin_amdgcn_readlane(myw, j + u);
                int src = word & 0x1FFFF;
                int dl  = word >> 17;
                float f0 = x[src * DIM + lane];
                float f1 = x[src * DIM + 64 + lane];
                atomicAdd(&acc[dl * DIM + lane], f0);
                atomicAdd(&acc[dl * DIM + 64 + lane], f1);
            }
        }
    }
    // tail chunk (belongs to exactly one wave)
    if (base < n) {
        int m = n - base;                                // 1..63
        int myw = (lane < m) ? bp[base + lane] : 0;
        if (lane < m) atomicAdd(&cnt[myw >> 17], 1);
        for (int j = 0; j < m; ++j) {
            int word = __builtin_amdgcn_readlane(myw, j);
            int src = word & 0x1FFFF;
            int dl  = word >> 17;
            float f0 = x[src * DIM + lane];
            float f1 = x[src * DIM + 64 + lane];
            atomicAdd(&acc[dl * DIM + lane], f0);
            atomicAdd(&acc[dl * DIM + 64 + lane], f1);
        }
    }
    __syncthreads();

    const int node0 = b * BK_NODES;
    for (int i = w; i < BK_NODES; i += 8) {
        int node = node0 + i;
        if (node >= N_NODES) break;
        float inv = 1.0f / fmaxf((float)cnt[i], 1.0f);
        a[node * DIM + lane]      = x[node * DIM + lane]      + acc[i * DIM + lane] * inv;
        a[node * DIM + 64 + lane] = x[node * DIM + 64 + lane] + acc[i * DIM + 64 + lane] * inv;
    }
}

// ===========================================================================
// GEMM1 + fused BN stats. In-place on ah (each block owns its 64 rows).
// ===========================================================================
__global__ __launch_bounds__(256) void gemm_agg_k(
    float* ah,
    const float* __restrict__ W, const float* __restrict__ bias,
    float* __restrict__ colsum, float* __restrict__ colsq)
{
    __shared__ float lds[64 * 132];
    const int t = threadIdx.x;
    const int row0 = blockIdx.x * 64;

    for (int i = t; i < 64 * 32; i += 256) {
        int r = i >> 5;
        int c = (i & 31) << 2;
        int gr = row0 + r;
        float4 v = make_float4(0.f, 0.f, 0.f, 0.f);
        if (gr < N_NODES) v = *(const float4*)(ah + gr * DIM + c);
        *(float4*)(lds + r * 132 + c) = v;
    }
    __syncthreads();

    const int tx = t & 15, ty = t >> 4;
    const int j0 = tx * 8;
    float acc[4][8];
    #pragma unroll
    for (int r = 0; r < 4; ++r)
        #pragma unroll
        for (int c = 0; c < 8; ++c) acc[r][c] = 0.f;

    #pragma unroll 4
    for (int k = 0; k < DIM; ++k) {
        float4 w0 = *(const float4*)(W + k * DIM + j0);
        float4 w1 = *(const float4*)(W + k * DIM + j0 + 4);
        float wv[8] = {w0.x, w0.y, w0.z, w0.w, w1.x, w1.y, w1.z, w1.w};
        #pragma unroll
        for (int r = 0; r < 4; ++r) {
            float a = lds[(ty * 4 + r) * 132 + k];
            #pragma unroll
            for (int c = 0; c < 8; ++c) acc[r][c] = fmaf(a, wv[c], acc[r][c]);
        }
    }

    float4 bv0 = *(const float4*)(bias + j0);
    float4 bv1 = *(const float4*)(bias + j0 + 4);
    float bb[8] = {bv0.x, bv0.y, bv0.z, bv0.w, bv1.x, bv1.y, bv1.z, bv1.w};
    float psum[8], psq[8];
    #pragma unroll
    for (int c = 0; c < 8; ++c) { psum[c] = 0.f; psq[c] = 0.f; }
    #pragma unroll
    for (int r = 0; r < 4; ++r) {
        int gr = row0 + ty * 4 + r;
        if (gr < N_NODES) {
            float vals[8];
            #pragma unroll
            for (int c = 0; c < 8; ++c) {
                float v = acc[r][c] + bb[c];
                vals[c] = v;
                psum[c] += v;
                psq[c] += v * v;
            }
            *(float4*)(ah + gr * DIM + j0)     = make_float4(vals[0], vals[1], vals[2], vals[3]);
            *(float4*)(ah + gr * DIM + j0 + 4) = make_float4(vals[4], vals[5], vals[6], vals[7]);
        }
    }

    __syncthreads();
    #pragma unroll
    for (int c = 0; c < 8; ++c) {
        lds[ty * 128 + j0 + c]        = psum[c];
        lds[2048 + ty * 128 + j0 + c] = psq[c];
    }
    __syncthreads();
    if (t < 128) {
        float ss = 0.f, sq = 0.f;
        #pragma unroll
        for (int u = 0; u < 16; ++u) {
            ss += lds[u * 128 + t];
            sq += lds[2048 + u * 128 + t];
        }
        atomicAdd(colsum + t, ss);
        atomicAdd(colsq + t, sq);
    }
}

__global__ void bnstats_k(const float* __restrict__ colsum, const float* __restrict__ colsq,
                          const float* __restrict__ gamma, const float* __restrict__ beta,
                          float* __restrict__ scale, float* __restrict__ shift)
{
    int j = threadIdx.x;
    const float inv_n = 1.0f / (float)N_NODES;
    float mu = colsum[j] * inv_n;
    float var = colsq[j] * inv_n - mu * mu;   // biased variance (torch BN)
    float sc = gamma[j] * rsqrtf(var + 1e-5f);
    scale[j] = sc;
    shift[j] = beta[j] - mu * sc;
}

// ===========================================================================
// GEMM2: out = relu_opt( relu(h1*scale+shift) @ W2 + b2 )
// ===========================================================================
__global__ __launch_bounds__(256) void gemm_bn_k(
    const float* __restrict__ h1, const float* __restrict__ scale, const float* __restrict__ shift,
    const float* __restrict__ W, const float* __restrict__ bias,
    float* __restrict__ out, int relu_out)
{
    __shared__ float lds[64 * 132];
    const int t = threadIdx.x;
    const int row0 = blockIdx.x * 64;

    for (int i = t; i < 64 * 32; i += 256) {
        int r = i >> 5;
        int c = (i & 31) << 2;
        int gr = row0 + r;
        float4 v = make_float4(0.f, 0.f, 0.f, 0.f);
        if (gr < N_NODES) {
            float4 hv = *(const float4*)(h1 + gr * DIM + c);
            float4 sc = *(const float4*)(scale + c);
            float4 sh = *(const float4*)(shift + c);
            v.x = fmaxf(hv.x * sc.x + sh.x, 0.f);
            v.y = fmaxf(hv.y * sc.y + sh.y, 0.f);
            v.z = fmaxf(hv.z * sc.z + sh.z, 0.f);
            v.w = fmaxf(hv.w * sc.w + sh.w, 0.f);
        }
        *(float4*)(lds + r * 132 + c) = v;
    }
    __syncthreads();

    const int tx = t & 15, ty = t >> 4;
    const int j0 = tx * 8;
    float acc[4][8];
    #pragma unroll
    for (int r = 0; r < 4; ++r)
        #pragma unroll
        for (int c = 0; c < 8; ++c) acc[r][c] = 0.f;

    #pragma unroll 4
    for (int k = 0; k < DIM; ++k) {
        float4 w0 = *(const float4*)(W + k * DIM + j0);
        float4 w1 = *(const float4*)(W + k * DIM + j0 + 4);
        float wv[8] = {w0.x, w0.y, w0.z, w0.w, w1.x, w1.y, w1.z, w1.w};
        #pragma unroll
        for (int r = 0; r < 4; ++r) {
            float a = lds[(ty * 4 + r) * 132 + k];
            #pragma unroll
            for (int c = 0; c < 8; ++c) acc[r][c] = fmaf(a, wv[c], acc[r][c]);
        }
    }

    float4 bv0 = *(const float4*)(bias + j0);
    float4 bv1 = *(const float4*)(bias + j0 + 4);
    float bb[8] = {bv0.x, bv0.y, bv0.z, bv0.w, bv1.x, bv1.y, bv1.z, bv1.w};
    #pragma unroll
    for (int r = 0; r < 4; ++r) {
        int gr = row0 + ty * 4 + r;
        if (gr < N_NODES) {
            float vals[8];
            #pragma unroll
            for (int c = 0; c < 8; ++c) {
                float v = acc[r][c] + bb[c];
                if (relu_out) v = fmaxf(v, 0.f);
                vals[c] = v;
            }
            *(float4*)(out + gr * DIM + j0)     = make_float4(vals[0], vals[1], vals[2], vals[3]);
            *(float4*)(out + gr * DIM + j0 + 4) = make_float4(vals[4], vals[5], vals[6], vals[7]);
        }
    }
}

// ---------------------------------------------------------------------------
// Workspace layout:
//   floats: ah (a/h1 aliased, 12.8M) @ 0; colsum@12.8M, colsq@+128,
//           scale@+256, shift@+384
//   ints (after 12,800,512 floats): bbuf[NBK*BCAP = 3,203,072], bcursor[NBK]
// Total ≈ 64.1 MB (R1 used 103 MB fine).
// ---------------------------------------------------------------------------
extern "C" void kernel_launch(void* const* d_in, const int* in_sizes, int n_in,
                              void* d_out, int out_size, void* d_ws, size_t ws_size,
                              hipStream_t stream)
{
    const float* x    = (const float*)d_in[0];
    const int*   ei   = (const int*)d_in[1];
    const float* W1_0 = (const float*)d_in[2];
    const float* b1_0 = (const float*)d_in[3];
    const float* g_0  = (const float*)d_in[4];
    const float* be_0 = (const float*)d_in[5];
    const float* W2_0 = (const float*)d_in[6];
    const float* b2_0 = (const float*)d_in[7];
    const float* W1_1 = (const float*)d_in[8];
    const float* b1_1 = (const float*)d_in[9];
    const float* g_1  = (const float*)d_in[10];
    const float* be_1 = (const float*)d_in[11];
    const float* W2_1 = (const float*)d_in[12];
    const float* b2_1 = (const float*)d_in[13];
    float* out = (float*)d_out;
    float* ws  = (float*)d_ws;

    float* ah     = ws;
    float* colsum = ws + 12800000;
    float* colsq  = colsum + 128;
    float* scale  = colsum + 256;
    float* shift  = colsum + 384;
    int* ibase    = (int*)(ws + 12800512);
    int* bbuf     = ibase;
    int* bcursor  = ibase + NBK * BCAP;

    dim3 blk(256);
    int edge_blocks = (N_EDGES + 255) / 256;           // 6250
    int gemm_blocks = (N_NODES + 63) / 64;             // 1563

    // ---- bucket build (shared by both layers) ----
    hipMemsetAsync(bcursor, 0, NBK * sizeof(int), stream);
    bfill_k<<<edge_blocks, blk, 0, stream>>>(ei, bcursor, bbuf);

    // ---- layer 0 ----
    hipMemsetAsync(colsum, 0, 256 * sizeof(float), stream);
    agg_fused_k<<<NBK, 512, 0, stream>>>(x, bcursor, bbuf, ah);
    gemm_agg_k<<<gemm_blocks, blk, 0, stream>>>(ah, W1_0, b1_0, colsum, colsq);
    bnstats_k<<<1, 128, 0, stream>>>(colsum, colsq, g_0, be_0, scale, shift);
    gemm_bn_k<<<gemm_blocks, blk, 0, stream>>>(ah, scale, shift, W2_0, b2_0, out, 1);

    // ---- layer 1 ----
    hipMemsetAsync(colsum, 0, 256 * sizeof(float), stream);
    agg_fused_k<<<NBK, 512, 0, stream>>>(out, bcursor, bbuf, ah);
    gemm_agg_k<<<gemm_blocks, blk, 0, stream>>>(ah, W1_1, b1_1, colsum, colsq);
    bnstats_k<<<1, 128, 0, stream>>>(colsum, colsq, g_1, be_1, scale, shift);
    gemm_bn_k<<<gemm_blocks, blk, 0, stream>>>(ah, scale, shift, W2_1, b2_1, out, 0);
}

// Round 5
// 730.658 us; speedup vs baseline: 4.7248x; 4.7248x over previous
//
#include <hip/hip_runtime.h>

#define N_NODES 100000
#define N_EDGES 1600000
#define DIM 128

#define SCAN_CHUNK 256
#define SCAN_BLOCKS ((N_NODES + SCAN_CHUNK - 1) / SCAN_CHUNK)   // 391

typedef __attribute__((ext_vector_type(8))) short bf16x8;
typedef __attribute__((ext_vector_type(4))) float f32x4;

__device__ inline unsigned short f2bf(float f) {
    unsigned u = __builtin_bit_cast(unsigned, f);
    return (unsigned short)((u + 0x7FFFu + ((u >> 16) & 1u)) >> 16);   // RNE
}

// ===========================================================================
// CSR build (identical to R3 — proven path)
// ===========================================================================
__global__ __launch_bounds__(256) void deg_k(const int* __restrict__ ei, int* __restrict__ deg)
{
    int e = blockIdx.x * 256 + threadIdx.x;
    if (e < N_EDGES) atomicAdd(deg + ei[N_EDGES + e], 1);
}

__global__ __launch_bounds__(256) void scan_reduce_k(const int* __restrict__ deg,
                                                     int* __restrict__ blocksum)
{
    __shared__ int red[256];
    int t = threadIdx.x;
    int i = blockIdx.x * SCAN_CHUNK + t;
    int v = (i < N_NODES) ? deg[i] : 0;
    red[t] = v;
    __syncthreads();
    #pragma unroll
    for (int off = 128; off > 0; off >>= 1) {
        if (t < off) red[t] += red[t + off];
        __syncthreads();
    }
    if (t == 0) blocksum[blockIdx.x] = red[0];
}

__global__ __launch_bounds__(512) void scan_blocks_k(const int* __restrict__ blocksum,
                                                     int* __restrict__ blockoff)
{
    __shared__ int part[512];
    int t = threadIdx.x;
    int v = (t < SCAN_BLOCKS) ? blocksum[t] : 0;
    part[t] = v;
    __syncthreads();
    #pragma unroll
    for (int off = 1; off < 512; off <<= 1) {
        int add = (t >= off) ? part[t - off] : 0;
        __syncthreads();
        part[t] += add;
        __syncthreads();
    }
    if (t < SCAN_BLOCKS) blockoff[t] = part[t] - v;
}

__global__ __launch_bounds__(256) void scan_final_k(const int* __restrict__ deg,
                                                    const int* __restrict__ blockoff,
                                                    int* __restrict__ rowptr,
                                                    int* __restrict__ cursor)
{
    __shared__ int part[256];
    int t = threadIdx.x;
    int i = blockIdx.x * SCAN_CHUNK + t;
    int v = (i < N_NODES) ? deg[i] : 0;
    part[t] = v;
    __syncthreads();
    #pragma unroll
    for (int off = 1; off < 256; off <<= 1) {
        int add = (t >= off) ? part[t - off] : 0;
        __syncthreads();
        part[t] += add;
        __syncthreads();
    }
    int excl = blockoff[blockIdx.x] + part[t] - v;
    if (i < N_NODES) {
        rowptr[i] = excl;
        cursor[i] = excl;
        if (i == N_NODES - 1) rowptr[N_NODES] = excl + v;
    }
}

__global__ __launch_bounds__(256) void fill_k(const int* __restrict__ ei,
                                              int* __restrict__ cursor,
                                              int* __restrict__ csr_src)
{
    int e = blockIdx.x * 256 + threadIdx.x;
    if (e >= N_EDGES) return;
    int src = ei[e];
    int dst = ei[N_EDGES + e];
    int pos = atomicAdd(cursor + dst, 1);
    csr_src[pos] = src;
}

// ===========================================================================
// Gather aggregation (R3 version — independent per-wave loads, good MLP)
// ===========================================================================
__global__ __launch_bounds__(256) void agg_k(const float* __restrict__ x,
                                             const int* __restrict__ rowptr,
                                             const int* __restrict__ csr_src,
                                             float* __restrict__ a)
{
    int wid = (blockIdx.x * 256 + threadIdx.x) >> 6;  // node id
    if (wid >= N_NODES) return;
    int lane = threadIdx.x & 63;
    int beg = rowptr[wid], end = rowptr[wid + 1];
    float ax = 0.f, ay = 0.f;
    int e = beg;
    for (; e + 4 <= end; e += 4) {
        int s0 = csr_src[e], s1 = csr_src[e + 1], s2 = csr_src[e + 2], s3 = csr_src[e + 3];
        float2 v0 = *(const float2*)(x + s0 * DIM + lane * 2);
        float2 v1 = *(const float2*)(x + s1 * DIM + lane * 2);
        float2 v2 = *(const float2*)(x + s2 * DIM + lane * 2);
        float2 v3 = *(const float2*)(x + s3 * DIM + lane * 2);
        ax += (v0.x + v1.x) + (v2.x + v3.x);
        ay += (v0.y + v1.y) + (v2.y + v3.y);
    }
    for (; e < end; ++e) {
        int s0 = csr_src[e];
        float2 v0 = *(const float2*)(x + s0 * DIM + lane * 2);
        ax += v0.x; ay += v0.y;
    }
    float inv = 1.0f / fmaxf((float)(end - beg), 1.0f);
    float2 xv = *(const float2*)(x + wid * DIM + lane * 2);
    float2 o;
    o.x = xv.x + ax * inv;
    o.y = xv.y + ay * inv;
    *(float2*)(a + wid * DIM + lane * 2) = o;
}

// ===========================================================================
// Weight transpose+convert: Wt[n*128+k] = bf16(W[k*128+n]). Tiny, once/call.
// ===========================================================================
__global__ __launch_bounds__(256) void wcvt_k(const float* __restrict__ W,
                                              unsigned short* __restrict__ Wt)
{
    int id = blockIdx.x * 256 + threadIdx.x;      // 16384
    int n = id >> 7, k = id & 127;
    Wt[n * DIM + k] = f2bf(W[k * DIM + n]);
}

// ===========================================================================
// MFMA GEMM1: h1 = A @ W1 + b1 (in-place on ah) + fused BN column stats.
// 128 rows/block, 256 thr (4 waves), each wave: 2 row-tiles x 8 col-tiles of
// 16x16x32 bf16 MFMA. A & Wt staged in LDS, stride 136 bf16 (16B-aligned,
// 2-way bank aliasing = free). Epilogue fp32.
// ===========================================================================
__global__ __launch_bounds__(256) void gemm1_mfma_k(
    float* ah, const unsigned short* __restrict__ Wt,
    const float* __restrict__ bias,
    float* __restrict__ colsum, float* __restrict__ colsq)
{
    __shared__ unsigned short Alds[128 * 136];
    __shared__ unsigned short Wlds[128 * 136];
    __shared__ float cstat[256];

    const int t = threadIdx.x;
    const int row0 = blockIdx.x * 128;
    if (t < 256) cstat[t] = 0.f;

    // stage A (fp32 -> bf16) and Wt (bf16 copy)
    for (int i = t; i < 2048; i += 256) {
        int r = i >> 4, seg = i & 15;
        int gr = row0 + r;
        bf16x8 o;
        if (gr < N_NODES) {
            const float* p = ah + gr * DIM + seg * 8;
            float4 v0 = *(const float4*)p;
            float4 v1 = *(const float4*)(p + 4);
            o[0] = (short)f2bf(v0.x); o[1] = (short)f2bf(v0.y);
            o[2] = (short)f2bf(v0.z); o[3] = (short)f2bf(v0.w);
            o[4] = (short)f2bf(v1.x); o[5] = (short)f2bf(v1.y);
            o[6] = (short)f2bf(v1.z); o[7] = (short)f2bf(v1.w);
        } else {
            o = (bf16x8)(short)0;
        }
        *(bf16x8*)(Alds + r * 136 + seg * 8) = o;
        *(bf16x8*)(Wlds + r * 136 + seg * 8) = *(const bf16x8*)(Wt + r * DIM + seg * 8);
    }
    __syncthreads();

    const int w = t >> 6, lane = t & 63;
    const int m = lane & 15, q = lane >> 4;

    f32x4 acc[2][8];
    #pragma unroll
    for (int i = 0; i < 2; ++i)
        #pragma unroll
        for (int ct = 0; ct < 8; ++ct) acc[i][ct] = (f32x4)0.f;

    #pragma unroll
    for (int kb = 0; kb < DIM; kb += 32) {
        bf16x8 af0 = *(bf16x8*)(Alds + ((w * 2 + 0) * 16 + m) * 136 + kb + q * 8);
        bf16x8 af1 = *(bf16x8*)(Alds + ((w * 2 + 1) * 16 + m) * 136 + kb + q * 8);
        #pragma unroll
        for (int ct = 0; ct < 8; ++ct) {
            bf16x8 bf = *(bf16x8*)(Wlds + (ct * 16 + m) * 136 + kb + q * 8);
            acc[0][ct] = __builtin_amdgcn_mfma_f32_16x16x32_bf16(af0, bf, acc[0][ct], 0, 0, 0);
            acc[1][ct] = __builtin_amdgcn_mfma_f32_16x16x32_bf16(af1, bf, acc[1][ct], 0, 0, 0);
        }
    }

    // epilogue: +bias, store h1 (fp32, in-place), BN partials -> LDS -> global
    #pragma unroll
    for (int ct = 0; ct < 8; ++ct) {
        int col = ct * 16 + m;
        float bb = bias[col];
        float ps = 0.f, pq = 0.f;
        #pragma unroll
        for (int i = 0; i < 2; ++i) {
            int rbase = row0 + (w * 2 + i) * 16 + q * 4;
            #pragma unroll
            for (int r = 0; r < 4; ++r) {
                int gr = rbase + r;
                if (gr < N_NODES) {
                    float v = acc[i][ct][r] + bb;
                    ah[gr * DIM + col] = v;
                    ps += v; pq += v * v;
                }
            }
        }
        atomicAdd(&cstat[col], ps);
        atomicAdd(&cstat[128 + col], pq);
    }
    __syncthreads();
    if (t < 128) {
        atomicAdd(colsum + t, cstat[t]);
        atomicAdd(colsq + t, cstat[128 + t]);
    }
}

__global__ void bnstats_k(const float* __restrict__ colsum, const float* __restrict__ colsq,
                          const float* __restrict__ gamma, const float* __restrict__ beta,
                          float* __restrict__ scale, float* __restrict__ shift)
{
    int j = threadIdx.x;
    const float inv_n = 1.0f / (float)N_NODES;
    float mu = colsum[j] * inv_n;
    float var = colsq[j] * inv_n - mu * mu;   // biased variance (torch BN)
    float sc = gamma[j] * rsqrtf(var + 1e-5f);
    scale[j] = sc;
    shift[j] = beta[j] - mu * sc;
}

// ===========================================================================
// MFMA GEMM2: out = [relu]( relu(h1*scale+shift) @ W2 + b2 ).
// BN+relu applied in fp32 during staging, then bf16.
// ===========================================================================
__global__ __launch_bounds__(256) void gemm2_mfma_k(
    const float* __restrict__ h1, const float* __restrict__ scale, const float* __restrict__ shift,
    const unsigned short* __restrict__ Wt, const float* __restrict__ bias,
    float* __restrict__ out, int relu_out)
{
    __shared__ unsigned short Alds[128 * 136];
    __shared__ unsigned short Wlds[128 * 136];
    __shared__ float ssc[256];                 // [0..127] scale, [128..255] shift

    const int t = threadIdx.x;
    const int row0 = blockIdx.x * 128;
    if (t < 128) { ssc[t] = scale[t]; ssc[128 + t] = shift[t]; }
    __syncthreads();

    for (int i = t; i < 2048; i += 256) {
        int r = i >> 4, seg = i & 15;
        int gr = row0 + r;
        bf16x8 o;
        if (gr < N_NODES) {
            const float* p = h1 + gr * DIM + seg * 8;
            float4 v0 = *(const float4*)p;
            float4 v1 = *(const float4*)(p + 4);
            int cb = seg * 8;
            float f[8] = {v0.x, v0.y, v0.z, v0.w, v1.x, v1.y, v1.z, v1.w};
            #pragma unroll
            for (int u = 0; u < 8; ++u) {
                float v = fmaxf(f[u] * ssc[cb + u] + ssc[128 + cb + u], 0.f);
                o[u] = (short)f2bf(v);
            }
        } else {
            o = (bf16x8)(short)0;
        }
        *(bf16x8*)(Alds + r * 136 + seg * 8) = o;
        *(bf16x8*)(Wlds + r * 136 + seg * 8) = *(const bf16x8*)(Wt + r * DIM + seg * 8);
    }
    __syncthreads();

    const int w = t >> 6, lane = t & 63;
    const int m = lane & 15, q = lane >> 4;

    f32x4 acc[2][8];
    #pragma unroll
    for (int i = 0; i < 2; ++i)
        #pragma unroll
        for (int ct = 0; ct < 8; ++ct) acc[i][ct] = (f32x4)0.f;

    #pragma unroll
    for (int kb = 0; kb < DIM; kb += 32) {
        bf16x8 af0 = *(bf16x8*)(Alds + ((w * 2 + 0) * 16 + m) * 136 + kb + q * 8);
        bf16x8 af1 = *(bf16x8*)(Alds + ((w * 2 + 1) * 16 + m) * 136 + kb + q * 8);
        #pragma unroll
        for (int ct = 0; ct < 8; ++ct) {
            bf16x8 bf = *(bf16x8*)(Wlds + (ct * 16 + m) * 136 + kb + q * 8);
            acc[0][ct] = __builtin_amdgcn_mfma_f32_16x16x32_bf16(af0, bf, acc[0][ct], 0, 0, 0);
            acc[1][ct] = __builtin_amdgcn_mfma_f32_16x16x32_bf16(af1, bf, acc[1][ct], 0, 0, 0);
        }
    }

    #pragma unroll
    for (int ct = 0; ct < 8; ++ct) {
        int col = ct * 16 + m;
        float bb = bias[col];
        #pragma unroll
        for (int i = 0; i < 2; ++i) {
            int rbase = row0 + (w * 2 + i) * 16 + q * 4;
            #pragma unroll
            for (int r = 0; r < 4; ++r) {
                int gr = rbase + r;
                if (gr < N_NODES) {
                    float v = acc[i][ct][r] + bb;
                    if (relu_out) v = fmaxf(v, 0.f);
                    out[gr * DIM + col] = v;
                }
            }
        }
    }
}

// ---------------------------------------------------------------------------
// Workspace layout:
//   floats: ah (a/h1 aliased, 12.8M) @ 0; colsum@12.8M, colsq@+128,
//           scale@+256, shift@+384
//   ints (@ ws+12800512): deg[100k], rowptr[100001], cursor[100k],
//           csr_src[1.6M], blocksum[391], blockoff[391]
//   ushorts (@ ibase+1901000, 16B-aligned): Wt x4, 16384 each
// ---------------------------------------------------------------------------
extern "C" void kernel_launch(void* const* d_in, const int* in_sizes, int n_in,
                              void* d_out, int out_size, void* d_ws, size_t ws_size,
                              hipStream_t stream)
{
    const float* x    = (const float*)d_in[0];
    const int*   ei   = (const int*)d_in[1];
    const float* W1_0 = (const float*)d_in[2];
    const float* b1_0 = (const float*)d_in[3];
    const float* g_0  = (const float*)d_in[4];
    const float* be_0 = (const float*)d_in[5];
    const float* W2_0 = (const float*)d_in[6];
    const float* b2_0 = (const float*)d_in[7];
    const float* W1_1 = (const float*)d_in[8];
    const float* b1_1 = (const float*)d_in[9];
    const float* g_1  = (const float*)d_in[10];
    const float* be_1 = (const float*)d_in[11];
    const float* W2_1 = (const float*)d_in[12];
    const float* b2_1 = (const float*)d_in[13];
    float* out = (float*)d_out;
    float* ws  = (float*)d_ws;

    float* ah     = ws;
    float* colsum = ws + 12800000;
    float* colsq  = colsum + 128;
    float* scale  = colsum + 256;
    float* shift  = colsum + 384;
    int* ibase    = (int*)(ws + 12800512);
    int* deg      = ibase;
    int* rowptr   = ibase + 100000;
    int* cursor   = ibase + 200001;
    int* csr_src  = ibase + 300001;
    int* blocksum = ibase + 1900001;
    int* blockoff = ibase + 1900501;
    unsigned short* wt10 = (unsigned short*)(ibase + 1901000);
    unsigned short* wt20 = wt10 + 16384;
    unsigned short* wt11 = wt10 + 32768;
    unsigned short* wt21 = wt10 + 49152;

    dim3 blk(256);
    int edge_blocks = (N_EDGES + 255) / 256;           // 6250
    int mfma_blocks = (N_NODES + 127) / 128;           // 782
    int agg_blocks  = (N_NODES * 64 + 255) / 256;      // 25000

    // ---- weight convert (once) + CSR build (shared by both layers) ----
    wcvt_k<<<64, blk, 0, stream>>>(W1_0, wt10);
    wcvt_k<<<64, blk, 0, stream>>>(W2_0, wt20);
    wcvt_k<<<64, blk, 0, stream>>>(W1_1, wt11);
    wcvt_k<<<64, blk, 0, stream>>>(W2_1, wt21);
    hipMemsetAsync(deg, 0, N_NODES * sizeof(int), stream);
    deg_k<<<edge_blocks, blk, 0, stream>>>(ei, deg);
    scan_reduce_k<<<SCAN_BLOCKS, blk, 0, stream>>>(deg, blocksum);
    scan_blocks_k<<<1, 512, 0, stream>>>(blocksum, blockoff);
    scan_final_k<<<SCAN_BLOCKS, blk, 0, stream>>>(deg, blockoff, rowptr, cursor);
    fill_k<<<edge_blocks, blk, 0, stream>>>(ei, cursor, csr_src);

    // ---- layer 0 ----
    hipMemsetAsync(colsum, 0, 256 * sizeof(float), stream);
    agg_k<<<agg_blocks, blk, 0, stream>>>(x, rowptr, csr_src, ah);
    gemm1_mfma_k<<<mfma_blocks, blk, 0, stream>>>(ah, wt10, b1_0, colsum, colsq);
    bnstats_k<<<1, 128, 0, stream>>>(colsum, colsq, g_0, be_0, scale, shift);
    gemm2_mfma_k<<<mfma_blocks, blk, 0, stream>>>(ah, scale, shift, wt20, b2_0, out, 1);

    // ---- layer 1 ----
    hipMemsetAsync(colsum, 0, 256 * sizeof(float), stream);
    agg_k<<<agg_blocks, blk, 0, stream>>>(out, rowptr, csr_src, ah);
    gemm1_mfma_k<<<mfma_blocks, blk, 0, stream>>>(ah, wt11, b1_1, colsum, colsq);
    bnstats_k<<<1, 128, 0, stream>>>(colsum, colsq, g_1, be_1, scale, shift);
    gemm2_mfma_k<<<mfma_blocks, blk, 0, stream>>>(ah, scale, shift, wt21, b2_1, out, 0);
}